// Round 11
// baseline (44.550 us; speedup 1.0000x reference)
//
#include <hip/hip_runtime.h>
#include <math.h>

#define BB 8
#define KK 4
#define CT 524288          // floats per (b,k) slice
#define GXB 64             // blocks per batch -> 512 blocks = 2/CU
#define NT 8               // tiles per block
#define TILE 256           // float4 positions per tile
#define TPB 512            // 8 waves
#define NBITS 2048
#define NACC 25            // 16 cross + 4 p2 + 4 t2 + 1 cons
#define NBLK (GXB*BB)      // 512
#define WS_BCE (NACC*NBLK) // ws[12800] = bce sum (written by block (0,0))

typedef float f32x2 __attribute__((ext_vector_type(2)));
typedef __attribute__((address_space(1))) const void GV;
typedef __attribute__((address_space(3))) void LV;

__device__ __forceinline__ void gl_lds16(const void* g, void* l) {
  __builtin_amdgcn_global_load_lds((GV*)g, (LV*)l, 16, 0, 0);
}

__global__ __launch_bounds__(TPB, 2) void floss_reduce(
    const float* __restrict__ sep, const float* __restrict__ src,
    const float* __restrict__ mix, const float* __restrict__ pred_bits,
    const int* __restrict__ target_bits, float* __restrict__ ws) {
  // [buf][stream][floats]: 2 * 9 * 1024 * 4B = 72 KB -> 2 blocks/CU
  __shared__ float smem[2][9][TILE * 4];
  __shared__ float redu[8][NACC];
  __shared__ float bces[8];

  const int b = blockIdx.y;
  const int tid  = threadIdx.x;
  const int wave = tid >> 6, lane = tid & 63;

  const float* sepb = sep + (size_t)b * KK * CT;
  const float* srcb = src + (size_t)b * KK * CT;
  const float* mixb = mix + (size_t)b * CT;
  const float* mybase = (wave < 4) ? (sepb + (size_t)wave * CT)
                                   : (srcb + (size_t)(wave - 4) * CT);

  const int tile0 = blockIdx.x * NT;

  // wave w DMAs its stream's 4 KB (4 x 1KB); waves 0-3 add one 1KB mix slice.
  auto stage = [&](int t, int c) {
    const size_t pbyte = (size_t)(tile0 + t) * TILE * 16;  // 4 KB per tile
    const char* gsrc = (const char*)mybase + pbyte + (size_t)lane * 16;
    float* ldst = &smem[c][wave][0];
    #pragma unroll
    for (int r = 0; r < 4; ++r)
      gl_lds16(gsrc + (size_t)r * 1024, ldst + r * 256);
    if (wave < 4) {
      const char* gmix = (const char*)mixb + pbyte + (size_t)wave * 1024
                       + (size_t)lane * 16;
      gl_lds16(gmix, &smem[c][8][wave * 256]);
    }
  };

  float cr[4][4] = {};
  float p2[4] = {};
  float t2[4] = {};
  float cons = 0.f;

  stage(0, 0);

  // block (0,0): fold BCE into the shadow of the first tile's DMA
  float bacc = 0.f;
  if (blockIdx.x == 0 && b == 0) {
    for (int i = tid; i < NBITS; i += TPB) {
      float tb = (float)target_bits[i];
      float p = fminf(fmaxf(pred_bits[i], 1e-7f), 1.f - 1e-7f);
      bacc += tb * logf(p) + (1.f - tb) * logf(1.f - p);
    }
  }

  const int p = tid >> 1, half = tid & 1;   // 2 threads share one position
  const int didx = p * 4 + half * 2;        // float index within stream slot

  for (int t = 0; t < NT; ++t) {
    const int c = t & 1;
    if (t + 1 < NT) {
      stage(t + 1, c ^ 1);
      __builtin_amdgcn_sched_barrier(0);
      if (wave < 4)
        asm volatile("s_waitcnt vmcnt(5)" ::: "memory");  // tile t's 5 done
      else
        asm volatile("s_waitcnt vmcnt(4)" ::: "memory");  // tile t's 4 done
    } else {
      __builtin_amdgcn_sched_barrier(0);
      asm volatile("s_waitcnt vmcnt(0)" ::: "memory");
    }
    __syncthreads();                                      // tile t fully landed

    f32x2 D[9];
    #pragma unroll
    for (int s = 0; s < 9; ++s)
      D[s] = *(const f32x2*)&smem[c][s][didx];

    #pragma unroll
    for (int l = 0; l < 2; ++l) {
      #pragma unroll
      for (int i = 0; i < 4; ++i) {
        float si = D[i][l], ti = D[4 + i][l];
        p2[i] += si * si;
        t2[i] += ti * ti;
        #pragma unroll
        for (int j = 0; j < 4; ++j) cr[i][j] += si * D[4 + j][l];
      }
      float sm = D[0][l] + D[1][l] + D[2][l] + D[3][l] - D[8][l];
      cons += sm * sm;
    }
    __syncthreads();   // buf c fully consumed before restage
  }

  float acc[NACC];
  #pragma unroll
  for (int i = 0; i < 4; ++i)
    #pragma unroll
    for (int j = 0; j < 4; ++j) acc[i * 4 + j] = cr[i][j];
  #pragma unroll
  for (int i = 0; i < 4; ++i) { acc[16 + i] = p2[i]; acc[20 + i] = t2[i]; }
  acc[24] = cons;

  #pragma unroll
  for (int a = 0; a < NACC; ++a) {
    #pragma unroll
    for (int off = 32; off > 0; off >>= 1)
      acc[a] += __shfl_down(acc[a], off);
  }
  if (lane == 0) {
    #pragma unroll
    for (int a = 0; a < NACC; ++a) redu[wave][a] = acc[a];
  }
  __syncthreads();
  if (tid < NACC) {
    float v = 0.f;
    #pragma unroll
    for (int w = 0; w < 8; ++w) v += redu[w][tid];
    // ws[(a*BB + b)*GXB + gx]
    ws[((size_t)tid * BB + b) * GXB + blockIdx.x] = v;
  }

  if (blockIdx.x == 0 && b == 0) {
    #pragma unroll
    for (int off = 32; off > 0; off >>= 1) bacc += __shfl_down(bacc, off);
    if (lane == 0) bces[wave] = bacc;
    __syncthreads();
    if (tid == 0) {
      float s = 0.f;
      #pragma unroll
      for (int w = 0; w < 8; ++w) s += bces[w];
      ws[WS_BCE] = s;   // plain store; kernel boundary guarantees visibility
    }
  }
}

__global__ __launch_bounds__(256) void floss_finalize(
    const float* __restrict__ ws, const float* __restrict__ flow_loss,
    float* __restrict__ out) {
  __shared__ float sums[BB * NACC];
  const int t = threadIdx.x;

  if (t < BB * NACC) {
    const int a = t >> 3, b = t & 7;
    const float4* p = (const float4*)(ws + ((size_t)a * BB + b) * GXB);
    float4 s4 = make_float4(0.f, 0.f, 0.f, 0.f);
    #pragma unroll
    for (int g = 0; g < GXB / 4; ++g) {
      float4 x = p[g];
      s4.x += x.x; s4.y += x.y; s4.z += x.z; s4.w += x.w;
    }
    sums[b * NACC + a] = s4.x + s4.y + s4.z + s4.w;
  }
  __syncthreads();

  if (t == 0) {
    float bce = -ws[WS_BCE] / (float)NBITS;
    float bit = bce * 0.5f;

    const float inv_n = 1.f / (float)CT;
    float recon_sum = 0.f;
    float cons_sum = 0.f;
    for (int b = 0; b < BB; ++b) {
      const float* w = sums + b * NACC;
      cons_sum += w[24];
      float cost[4][4];
      for (int i = 0; i < 4; ++i)
        for (int j = 0; j < 4; ++j)
          cost[i][j] = (w[16 + i] + w[20 + j] - 2.f * w[i * 4 + j]) * inv_n;
      bool used[4] = {false, false, false, false};
      for (int i = 0; i < 4; ++i) {
        int bj = 0; float bv = INFINITY;
        for (int j = 0; j < 4; ++j) {
          if (!used[j] && cost[i][j] < bv) { bv = cost[i][j]; bj = j; }
        }
        recon_sum += bv; used[bj] = true;
      }
    }
    float recon = recon_sum / (float)BB * 0.1f;
    float cons = cons_sum / (float)(BB * CT) * 0.1f;
    float flow = flow_loss[0];
    out[0] = flow;
    out[1] = recon;
    out[2] = cons;
    out[3] = bit;
    out[4] = flow + recon + cons + bit;
  }
}

extern "C" void kernel_launch(void* const* d_in, const int* in_sizes, int n_in,
                              void* d_out, int out_size, void* d_ws, size_t ws_size,
                              hipStream_t stream) {
  const float* sep       = (const float*)d_in[0];
  const float* src       = (const float*)d_in[1];
  const float* mix       = (const float*)d_in[2];
  const float* pred_bits = (const float*)d_in[3];
  const float* flow      = (const float*)d_in[4];
  const int*   tgt_bits  = (const int*)d_in[5];
  float* ws = (float*)d_ws;

  floss_reduce<<<dim3(GXB, BB), TPB, 0, stream>>>(
      sep, src, mix, pred_bits, tgt_bits, ws);
  floss_finalize<<<1, 256, 0, stream>>>(ws, flow, (float*)d_out);
}

// Round 12
// 39.689 us; speedup vs baseline: 1.1225x; 1.1225x over previous
//
#include <hip/hip_runtime.h>
#include <math.h>

#define BB 8
#define KK 4
#define CT 524288          // floats per (b,k) slice
#define GXB 32             // blocks per batch -> 256 blocks = 1/CU
#define NT 8               // tiles per block
#define TILE 512           // float4 positions per tile
#define TPB 512            // 8 waves
#define NBITS 2048
#define NACC 25            // 16 cross + 4 p2 + 4 t2 + 1 cons
#define NBLK (GXB*BB)      // 256
#define WS_BCE (NACC*NBLK) // ws[6400] = bce sum (written by block (0,0))

typedef float f32x4 __attribute__((ext_vector_type(4)));
typedef __attribute__((address_space(1))) const void GV;
typedef __attribute__((address_space(3))) void LV;

__device__ __forceinline__ void gl_lds16(const void* g, void* l) {
  __builtin_amdgcn_global_load_lds((GV*)g, (LV*)l, 16, 0, 0);
}

__global__ __launch_bounds__(TPB, 1) void floss_reduce(
    const float* __restrict__ sep, const float* __restrict__ src,
    const float* __restrict__ mix, const float* __restrict__ pred_bits,
    const int* __restrict__ target_bits, float* __restrict__ ws) {
  // [buf][stream][floats]: 2 * 9 * 2048 * 4B = 144 KB
  __shared__ float smem[2][9][TILE * 4];
  __shared__ float redu[8][NACC];
  __shared__ float bces[8];

  const int b = blockIdx.y;
  const int tid  = threadIdx.x;
  const int wave = tid >> 6, lane = tid & 63;

  const float* sepb = sep + (size_t)b * KK * CT;
  const float* srcb = src + (size_t)b * KK * CT;
  const float* mixb = mix + (size_t)b * CT;
  const float* mybase = (wave < 4) ? (sepb + (size_t)wave * CT)
                                   : (srcb + (size_t)(wave - 4) * CT);

  const int tile0 = blockIdx.x * NT;

  // wave w DMAs its stream's 8 KB (8 x 1KB) + 1 KB of mix. 9 requests/wave.
  auto stage = [&](int t, int c) {
    const size_t pbyte = (size_t)(tile0 + t) * TILE * 16;
    const char* gsrc = (const char*)mybase + pbyte + (size_t)lane * 16;
    float* ldst = &smem[c][wave][0];
    #pragma unroll
    for (int r = 0; r < 8; ++r)
      gl_lds16(gsrc + (size_t)r * 1024, ldst + r * 256);
    const char* gmix = (const char*)mixb + pbyte + (size_t)wave * 1024 + (size_t)lane * 16;
    gl_lds16(gmix, &smem[c][8][wave * 256]);
  };

  float cr[4][4] = {};
  float p2[4] = {};
  float t2[4] = {};
  float cons = 0.f;

  stage(0, 0);

  // block (0,0): fold BCE into the shadow of the first tile's DMA
  float bacc = 0.f;
  if (blockIdx.x == 0 && b == 0) {
    for (int i = tid; i < NBITS; i += TPB) {
      float tb = (float)target_bits[i];
      float p = fminf(fmaxf(pred_bits[i], 1e-7f), 1.f - 1e-7f);
      bacc += tb * logf(p) + (1.f - tb) * logf(1.f - p);
    }
  }

  for (int t = 0; t < NT; ++t) {
    const int c = t & 1;
    if (t + 1 < NT) {
      stage(t + 1, c ^ 1);
      __builtin_amdgcn_sched_barrier(0);
      asm volatile("s_waitcnt vmcnt(9)" ::: "memory");  // tile t's 9 done
    } else {
      __builtin_amdgcn_sched_barrier(0);
      asm volatile("s_waitcnt vmcnt(0)" ::: "memory");
    }
    __syncthreads();                                    // all waves' tile t landed

    f32x4 D[9];
    #pragma unroll
    for (int s = 0; s < 9; ++s)
      D[s] = *(const f32x4*)&smem[c][s][tid * 4];

    #pragma unroll
    for (int l = 0; l < 4; ++l) {
      #pragma unroll
      for (int i = 0; i < 4; ++i) {
        float si = D[i][l], ti = D[4 + i][l];
        p2[i] += si * si;
        t2[i] += ti * ti;
        #pragma unroll
        for (int j = 0; j < 4; ++j) cr[i][j] += si * D[4 + j][l];
      }
      float sm = D[0][l] + D[1][l] + D[2][l] + D[3][l] - D[8][l];
      cons += sm * sm;
    }
    __syncthreads();   // buf c fully consumed before restage
  }

  float acc[NACC];
  #pragma unroll
  for (int i = 0; i < 4; ++i)
    #pragma unroll
    for (int j = 0; j < 4; ++j) acc[i * 4 + j] = cr[i][j];
  #pragma unroll
  for (int i = 0; i < 4; ++i) { acc[16 + i] = p2[i]; acc[20 + i] = t2[i]; }
  acc[24] = cons;

  #pragma unroll
  for (int a = 0; a < NACC; ++a) {
    #pragma unroll
    for (int off = 32; off > 0; off >>= 1)
      acc[a] += __shfl_down(acc[a], off);
  }
  if (lane == 0) {
    #pragma unroll
    for (int a = 0; a < NACC; ++a) redu[wave][a] = acc[a];
  }
  __syncthreads();
  if (tid < NACC) {
    float v = 0.f;
    #pragma unroll
    for (int w = 0; w < 8; ++w) v += redu[w][tid];
    // ws[(a*BB + b)*GXB + gx]
    ws[((size_t)tid * BB + b) * GXB + blockIdx.x] = v;
  }

  if (blockIdx.x == 0 && b == 0) {
    #pragma unroll
    for (int off = 32; off > 0; off >>= 1) bacc += __shfl_down(bacc, off);
    if (lane == 0) bces[wave] = bacc;
    __syncthreads();
    if (tid == 0) {
      float s = 0.f;
      #pragma unroll
      for (int w = 0; w < 8; ++w) s += bces[w];
      ws[WS_BCE] = s;   // plain store; next kernel launch guarantees visibility
    }
  }
}

__global__ __launch_bounds__(256) void floss_finalize(
    const float* __restrict__ ws, const float* __restrict__ flow_loss,
    float* __restrict__ out) {
  __shared__ float sums[BB * NACC];
  const int t = threadIdx.x;

  if (t < BB * NACC) {
    const int a = t >> 3, b = t & 7;
    const float4* p = (const float4*)(ws + ((size_t)a * BB + b) * GXB);
    float4 s4 = make_float4(0.f, 0.f, 0.f, 0.f);
    #pragma unroll
    for (int g = 0; g < GXB / 4; ++g) {
      float4 x = p[g];
      s4.x += x.x; s4.y += x.y; s4.z += x.z; s4.w += x.w;
    }
    sums[b * NACC + a] = s4.x + s4.y + s4.z + s4.w;
  }
  __syncthreads();

  if (t == 0) {
    float bce = -ws[WS_BCE] / (float)NBITS;
    float bit = bce * 0.5f;

    const float inv_n = 1.f / (float)CT;
    float recon_sum = 0.f;
    float cons_sum = 0.f;
    for (int b = 0; b < BB; ++b) {
      const float* w = sums + b * NACC;
      cons_sum += w[24];
      float cost[4][4];
      for (int i = 0; i < 4; ++i)
        for (int j = 0; j < 4; ++j)
          cost[i][j] = (w[16 + i] + w[20 + j] - 2.f * w[i * 4 + j]) * inv_n;
      bool used[4] = {false, false, false, false};
      for (int i = 0; i < 4; ++i) {
        int bj = 0; float bv = INFINITY;
        for (int j = 0; j < 4; ++j) {
          if (!used[j] && cost[i][j] < bv) { bv = cost[i][j]; bj = j; }
        }
        recon_sum += bv; used[bj] = true;
      }
    }
    float recon = recon_sum / (float)BB * 0.1f;
    float cons = cons_sum / (float)(BB * CT) * 0.1f;
    float flow = flow_loss[0];
    out[0] = flow;
    out[1] = recon;
    out[2] = cons;
    out[3] = bit;
    out[4] = flow + recon + cons + bit;
  }
}

extern "C" void kernel_launch(void* const* d_in, const int* in_sizes, int n_in,
                              void* d_out, int out_size, void* d_ws, size_t ws_size,
                              hipStream_t stream) {
  const float* sep       = (const float*)d_in[0];
  const float* src       = (const float*)d_in[1];
  const float* mix       = (const float*)d_in[2];
  const float* pred_bits = (const float*)d_in[3];
  const float* flow      = (const float*)d_in[4];
  const int*   tgt_bits  = (const int*)d_in[5];
  float* ws = (float*)d_ws;

  floss_reduce<<<dim3(GXB, BB), TPB, 0, stream>>>(
      sep, src, mix, pred_bits, tgt_bits, ws);
  floss_finalize<<<1, 256, 0, stream>>>(ws, flow, (float*)d_out);
}